// Round 2
// baseline (868.578 us; speedup 1.0000x reference)
//
#include <hip/hip_runtime.h>
#include <hip/hip_fp16.h>

#define S_LEN 2048
#define D_DIM 64

typedef __attribute__((ext_vector_type(8))) _Float16 half8;
typedef __attribute__((ext_vector_type(4))) _Float16 half4;
typedef __attribute__((ext_vector_type(4))) float   floatx4;

static constexpr size_t NELEM = (size_t)2 * 16 * 2048 * 64;  // 4,194,304 per tensor

// ---------------------------------------------------------------------------
// Kernel 1: fp32 -> fp16 conversion. Qh = q * 0.125 (fold in 1/sqrt(d)),
// Kh = k, Vt = V^T per (b,h): [bh][d=64][s=2048] so PV B-frags are contiguous.
// ---------------------------------------------------------------------------
__global__ __launch_bounds__(256) void cvt_kernel(const float* __restrict__ q,
                                                  const float* __restrict__ k,
                                                  const float* __restrict__ v,
                                                  _Float16* __restrict__ Qh,
                                                  _Float16* __restrict__ Kh,
                                                  _Float16* __restrict__ Vt) {
  __shared__ float lds[64][65];
  const int t  = threadIdx.x;
  const int bh = blockIdx.x >> 5;
  const int st = blockIdx.x & 31;
  const size_t base = (size_t)bh * (S_LEN * D_DIM) + (size_t)st * (64 * D_DIM);

#pragma unroll
  for (int i = 0; i < 4; ++i) {
    size_t e = base + (size_t)(t + 256 * i) * 4;
    floatx4 qv = *(const floatx4*)(q + e);
    floatx4 kv = *(const floatx4*)(k + e);
    half4 qh, kh;
#pragma unroll
    for (int j = 0; j < 4; ++j) {
      qh[j] = (_Float16)(qv[j] * 0.125f);
      kh[j] = (_Float16)kv[j];
    }
    *(half4*)(Qh + e) = qh;
    *(half4*)(Kh + e) = kh;
  }

  {
    const int row = t >> 2;
    const int c4  = t & 3;
#pragma unroll
    for (int i = 0; i < 4; ++i) {
      int col = (c4 + 4 * i) * 4;
      floatx4 vv = *(const floatx4*)(v + base + (size_t)row * D_DIM + col);
      lds[row][col + 0] = vv[0];
      lds[row][col + 1] = vv[1];
      lds[row][col + 2] = vv[2];
      lds[row][col + 3] = vv[3];
    }
  }
  __syncthreads();
  {
    const int d = t >> 2;
    const int j = t & 3;
    half8 t0, t1;
#pragma unroll
    for (int u = 0; u < 8; ++u) t0[u] = (_Float16)lds[j * 16 + u][d];
#pragma unroll
    for (int u = 0; u < 8; ++u) t1[u] = (_Float16)lds[j * 16 + 8 + u][d];
    size_t ob = (size_t)bh * (D_DIM * S_LEN) + (size_t)d * S_LEN + st * 64 + j * 16;
    *(half8*)(Vt + ob)     = t0;
    *(half8*)(Vt + ob + 8) = t1;
  }
}

// ---------------------------------------------------------------------------
// Kernel 2: barrier-free fused attention. One WG = one (b,h) x 64 q-rows,
// 4 waves x 16 q-rows. NO LDS staging of K/V: MFMA B-fragments are loaded
// directly from global (per-lane 16B, full-line coalesced, L2-served --
// K is 256KB per (b,h), L2-resident, shared by 32 blocks). The only LDS use
// is the wave-PRIVATE W round-trip (C-layout -> A-layout) which needs no
// __syncthreads (in-order DS within a wave), and the mask vector (one
// barrier at kernel start). Waves run fully independently; latency is
// hidden by 16 waves/CU instead of being exposed at 160 barriers.
// wout is written from the A-layout readback: 8 contiguous fp16 -> fp32 ->
// 2x global_store_dwordx4 (32B/lane contiguous) instead of 16 scalar
// strided stores. fp16 weight quantization: abs err <= ~5e-4 << 1.3e-2.
// ---------------------------------------------------------------------------
__global__ __launch_bounds__(256) void attn_kernel(
    const _Float16* __restrict__ Qh, const _Float16* __restrict__ Kh,
    const _Float16* __restrict__ Vt, const int* __restrict__ mask,
    float* __restrict__ out, float* __restrict__ wout) {
  __shared__ _Float16 ldsW[4][16][68];  // per-wave private 16x64 tile, pad 68
  __shared__ float maskf[S_LEN];

  const int t    = threadIdx.x;
  const int bh   = blockIdx.x >> 5;
  const int qt   = blockIdx.x & 31;
  const int b    = bh >> 4;  // H = 16
  const int q0   = qt * 64;
  const int wv   = t >> 6;
  const int lane = t & 63;
  const int l15  = lane & 15;
  const int quad = lane >> 4;

  const int* mrow = mask + (size_t)b * S_LEN;
#pragma unroll
  for (int i = 0; i < 8; ++i) {
    int idx = t + 256 * i;
    maskf[idx] = mrow[idx] ? 1.0f : 0.0f;
  }

  // Q fragments live in registers for the whole kernel (m = lane&15 row)
  const _Float16* Qp = Qh + ((size_t)bh * S_LEN + q0 + wv * 16 + l15) * D_DIM;
  const half8 qf0 = *(const half8*)(Qp + quad * 8);
  const half8 qf1 = *(const half8*)(Qp + 32 + quad * 8);

  const _Float16* Kbh = Kh + (size_t)bh * (S_LEN * D_DIM);
  const _Float16* Vbh = Vt + (size_t)bh * (D_DIM * S_LEN);

  __syncthreads();  // maskf ready -- the ONLY barrier in this kernel

  // ---- phase 1: row sums of exp(scores) ----
  float esum[4] = {0.f, 0.f, 0.f, 0.f};
#pragma unroll 2
  for (int kt = 0; kt < 32; ++kt) {
#pragma unroll
    for (int n = 0; n < 4; ++n) {
      const _Float16* kp = Kbh + (size_t)(kt * 64 + n * 16 + l15) * D_DIM + quad * 8;
      half8 b0 = *(const half8*)kp;
      half8 b1 = *(const half8*)(kp + 32);
      floatx4 s = {0.f, 0.f, 0.f, 0.f};
      s = __builtin_amdgcn_mfma_f32_16x16x32_f16(qf0, b0, s, 0, 0, 0);
      s = __builtin_amdgcn_mfma_f32_16x16x32_f16(qf1, b1, s, 0, 0, 0);
      float mv = maskf[kt * 64 + n * 16 + l15];
#pragma unroll
      for (int r = 0; r < 4; ++r) esum[r] += mv * __expf(s[r]);
    }
  }
  float linv[4];
#pragma unroll
  for (int r = 0; r < 4; ++r) {
    float vs = esum[r];
    vs += __shfl_xor(vs, 1);
    vs += __shfl_xor(vs, 2);
    vs += __shfl_xor(vs, 4);
    vs += __shfl_xor(vs, 8);
    linv[r] = 1.0f / vs;
  }

  // ---- phase 2: weights out + O accumulate ----
  floatx4 oacc[4];
#pragma unroll
  for (int nd = 0; nd < 4; ++nd) oacc[nd] = (floatx4){0.f, 0.f, 0.f, 0.f};

  float* wr = wout + ((size_t)bh * S_LEN + q0 + wv * 16 + l15) * S_LEN;
  for (int kt = 0; kt < 32; ++kt) {
#pragma unroll
    for (int n = 0; n < 4; ++n) {
      const _Float16* kp = Kbh + (size_t)(kt * 64 + n * 16 + l15) * D_DIM + quad * 8;
      half8 b0 = *(const half8*)kp;
      half8 b1 = *(const half8*)(kp + 32);
      floatx4 s = {0.f, 0.f, 0.f, 0.f};
      s = __builtin_amdgcn_mfma_f32_16x16x32_f16(qf0, b0, s, 0, 0, 0);
      s = __builtin_amdgcn_mfma_f32_16x16x32_f16(qf1, b1, s, 0, 0, 0);
      float mv = maskf[kt * 64 + n * 16 + l15];
#pragma unroll
      for (int r = 0; r < 4; ++r) {
        float w = mv * __expf(s[r]) * linv[r];
        ldsW[wv][quad * 4 + r][n * 16 + l15] = (_Float16)w;
      }
    }
    // wave-private LDS round-trip: DS ops are in-order within a wave, and
    // the compiler preserves store->load order on the may-aliasing ldsW.
#pragma unroll
    for (int c = 0; c < 2; ++c) {
      half8 af = *(half8*)&ldsW[wv][l15][c * 32 + quad * 8];
      floatx4 w0, w1;
#pragma unroll
      for (int j = 0; j < 4; ++j) {
        w0[j] = (float)af[j];
        w1[j] = (float)af[4 + j];
      }
      float* wp = wr + kt * 64 + c * 32 + quad * 8;
      *(floatx4*)(wp)     = w0;
      *(floatx4*)(wp + 4) = w1;
#pragma unroll
      for (int nd = 0; nd < 4; ++nd) {
        const _Float16* vp = Vbh + (size_t)(nd * 16 + l15) * S_LEN + kt * 64 + c * 32 + quad * 8;
        half8 bf = *(const half8*)vp;
        oacc[nd] = __builtin_amdgcn_mfma_f32_16x16x32_f16(af, bf, oacc[nd], 0, 0, 0);
      }
    }
  }

#pragma unroll
  for (int nd = 0; nd < 4; ++nd)
#pragma unroll
    for (int r = 0; r < 4; ++r) {
      int qrow = wv * 16 + quad * 4 + r;
      out[((size_t)bh * S_LEN + q0 + qrow) * D_DIM + nd * 16 + l15] = oacc[nd][r];
    }
}

extern "C" void kernel_launch(void* const* d_in, const int* in_sizes, int n_in,
                              void* d_out, int out_size, void* d_ws, size_t ws_size,
                              hipStream_t stream) {
  (void)in_sizes; (void)n_in; (void)out_size; (void)ws_size;
  const float* q = (const float*)d_in[0];
  const float* k = (const float*)d_in[1];
  const float* v = (const float*)d_in[2];
  const int* mask = (const int*)d_in[3];

  float* out  = (float*)d_out;          // (B,H,S,D)
  float* wout = out + NELEM;            // (B,H,S,S)

  _Float16* Qh = (_Float16*)d_ws;       // 8 MiB
  _Float16* Kh = Qh + NELEM;            // 8 MiB
  _Float16* Vt = Kh + NELEM;            // 8 MiB (transposed V)

  cvt_kernel<<<dim3(1024), dim3(256), 0, stream>>>(q, k, v, Qh, Kh, Vt);
  attn_kernel<<<dim3(1024), dim3(256), 0, stream>>>(Qh, Kh, Vt, mask, out, wout);
}